// Round 1
// baseline (690.244 us; speedup 1.0000x reference)
//
#include <hip/hip_runtime.h>

#define NN 100000
#define NE 1600000
#define CH 128

// ---------------- CSR build ----------------

__global__ __launch_bounds__(256) void k_count(const int* __restrict__ dst, int* __restrict__ degi) {
    int e = blockIdx.x * 256 + threadIdx.x;
    if (e < NE) atomicAdd(&degi[dst[e]], 1);
}

// block scans 1024 elements (256 thr x 4); writes local-exclusive prefix + block sum
__global__ __launch_bounds__(256) void k_scan1(const int* __restrict__ degi, int* __restrict__ rowptr,
                                               int* __restrict__ bsums) {
    __shared__ int tsum[256];
    int tid = threadIdx.x;
    int base = blockIdx.x * 1024 + tid * 4;
    int v[4];
    #pragma unroll
    for (int j = 0; j < 4; ++j) v[j] = (base + j < NN) ? degi[base + j] : 0;
    int s = v[0] + v[1] + v[2] + v[3];
    tsum[tid] = s;
    __syncthreads();
    for (int off = 1; off < 256; off <<= 1) {
        int t = (tid >= off) ? tsum[tid - off] : 0;
        __syncthreads();
        tsum[tid] += t;
        __syncthreads();
    }
    int run = tsum[tid] - s;  // exclusive prefix of this thread's chunk
    #pragma unroll
    for (int j = 0; j < 4; ++j) {
        if (base + j < NN) rowptr[base + j] = run;
        run += v[j];
    }
    if (tid == 255) bsums[blockIdx.x] = tsum[255];
}

__global__ __launch_bounds__(128) void k_scan2(int* __restrict__ bsums, int nsb) {
    __shared__ int sh[128];
    int tid = threadIdx.x;
    int v = (tid < nsb) ? bsums[tid] : 0;
    sh[tid] = v;
    __syncthreads();
    for (int off = 1; off < 128; off <<= 1) {
        int t = (tid >= off) ? sh[tid - off] : 0;
        __syncthreads();
        sh[tid] += t;
        __syncthreads();
    }
    if (tid < nsb) bsums[tid] = sh[tid] - v;
}

__global__ __launch_bounds__(256) void k_scan3(int* __restrict__ rowptr, const int* __restrict__ bsums,
                                               const int* __restrict__ degi, float* __restrict__ invd) {
    int b = blockIdx.x;
    int off = bsums[b];
    int tid = threadIdx.x;
    #pragma unroll
    for (int k = 0; k < 4; ++k) {
        int i = b * 1024 + k * 256 + tid;
        if (i < NN) {
            rowptr[i] += off;
            invd[i] = 1.0f / fmaxf((float)degi[i], 1.0f);
        }
    }
    if (b == 0 && tid == 0) rowptr[NN] = NE;
}

__global__ __launch_bounds__(256) void k_fill(const int* __restrict__ src, const int* __restrict__ dst,
                                              const int* __restrict__ rowptr, int* __restrict__ fill,
                                              int* __restrict__ col) {
    int e = blockIdx.x * 256 + threadIdx.x;
    if (e < NE) {
        int d = dst[e];
        int pos = rowptr[d] + atomicAdd(&fill[d], 1);
        col[pos] = src[e];
    }
}

// ---------------- mean aggregation: one 64-thread wave per node ----------------

__global__ __launch_bounds__(64) void k_agg(const float2* __restrict__ feat, const int* __restrict__ col,
                                            const int* __restrict__ rowptr, const float* __restrict__ invd,
                                            float2* __restrict__ out) {
    int n = blockIdx.x;
    int t = threadIdx.x;  // channel pair t -> channels 2t,2t+1
    int s = rowptr[n], e = rowptr[n + 1];
    float ax = 0.f, ay = 0.f;
    for (int i = s; i < e; ++i) {
        int c = col[i];
        float2 v = feat[(size_t)c * 64 + t];
        ax += v.x;
        ay += v.y;
    }
    float id = invd[n];
    float2 r;
    r.x = ax * id;
    r.y = ay * id;
    out[(size_t)n * 64 + t] = r;
}

// ---------------- fused GEMM: out = relu([mean | x] @ [Wl;Wr] + b) ----------------
// M x 128, K = 256. BM=64 BN=128 BK=32, 256 threads, 8x4 register tile.

__global__ __launch_bounds__(256) void k_gemm(const float* __restrict__ Amean, const float* __restrict__ Ax,
                                              const float* __restrict__ Wl, const float* __restrict__ Wr,
                                              const float* __restrict__ bias, float* __restrict__ out, int M) {
    __shared__ __align__(16) float As[32][68];   // [kk][row], padded stride 68 (16B aligned rows)
    __shared__ __align__(16) float Bs[32][128];  // [kk][col]
    int tid = threadIdx.x;
    int bm = blockIdx.x * 64;
    int tx = tid & 31;   // col group -> cols tx*4..tx*4+3
    int ty = tid >> 5;   // row group -> rows ty*8..ty*8+7
    float acc[8][4] = {};

    for (int kb = 0; kb < 8; ++kb) {
        const float* A = (kb < 4) ? Amean : Ax;
        const float* W = (kb < 4) ? Wl : Wr;
        int k0 = (kb & 3) * 32;
        // A tile: row = tid/4 (0..63), kk = (tid%4)*8 + j
        {
            int row = tid >> 2;
            int kk = (tid & 3) * 8;
            int gr = bm + row;
            if (gr < M) {
                const float* sp = A + (size_t)gr * 128 + k0 + kk;
                #pragma unroll
                for (int j = 0; j < 8; ++j) As[kk + j][row] = sp[j];
            } else {
                #pragma unroll
                for (int j = 0; j < 8; ++j) As[kk + j][row] = 0.f;
            }
        }
        // B tile: kk = tid/8 (0..31), cols (tid%8)*16 .. +15
        {
            int kk = tid >> 3;
            int c0 = (tid & 7) * 16;
            const float4* sp = (const float4*)(W + (size_t)(k0 + kk) * 128 + c0);
            float4* dp = (float4*)&Bs[kk][c0];
            dp[0] = sp[0];
            dp[1] = sp[1];
            dp[2] = sp[2];
            dp[3] = sp[3];
        }
        __syncthreads();
        #pragma unroll
        for (int kk = 0; kk < 32; ++kk) {
            float a[8], b[4];
            #pragma unroll
            for (int r = 0; r < 8; ++r) a[r] = As[kk][ty * 8 + r];
            #pragma unroll
            for (int c = 0; c < 4; ++c) b[c] = Bs[kk][tx * 4 + c];
            #pragma unroll
            for (int r = 0; r < 8; ++r)
                #pragma unroll
                for (int c = 0; c < 4; ++c) acc[r][c] += a[r] * b[c];
        }
        __syncthreads();
    }
    #pragma unroll
    for (int r = 0; r < 8; ++r) {
        int gr = bm + ty * 8 + r;
        if (gr < M) {
            #pragma unroll
            for (int c = 0; c < 4; ++c) {
                int gc = tx * 4 + c;
                float v = acc[r][c] + bias[gc];
                out[(size_t)gr * 128 + gc] = v > 0.f ? v : 0.f;
            }
        }
    }
}

// ---------------- launch ----------------

static inline size_t alignup(size_t x) { return (x + 255) & ~(size_t)255; }

extern "C" void kernel_launch(void* const* d_in, const int* in_sizes, int n_in,
                              void* d_out, int out_size, void* d_ws, size_t ws_size,
                              hipStream_t stream) {
    const float* x   = (const float*)d_in[0];
    const int* edge  = (const int*)d_in[1];  // [2][NE]: row0=src, row1=dst
    const float* Wl1 = (const float*)d_in[2];
    const float* Wr1 = (const float*)d_in[3];
    const float* b1  = (const float*)d_in[4];
    const float* Wl2 = (const float*)d_in[5];
    const float* Wr2 = (const float*)d_in[6];
    const float* b2  = (const float*)d_in[7];
    float* out = (float*)d_out;

    const int* srcp = edge;
    const int* dstp = edge + NE;

    char* w = (char*)d_ws;
    int* degi = (int*)w;              w += alignup((size_t)NN * 4);
    int* fill = (int*)w;              w += alignup((size_t)NN * 4);
    int* rowptr = (int*)w;            w += alignup((size_t)(NN + 1) * 4);
    int* bsums = (int*)w;             w += alignup(128 * 4);
    float* invd = (float*)w;          w += alignup((size_t)NN * 4);
    int* col = (int*)w;               w += alignup((size_t)NE * 4);
    float* mean = (float*)w;          w += alignup((size_t)NN * CH * 4);

    hipMemsetAsync(degi, 0, (size_t)NN * 4, stream);
    hipMemsetAsync(fill, 0, (size_t)NN * 4, stream);

    int nsb = (NN + 1023) / 1024;  // 98
    k_count<<<(NE + 255) / 256, 256, 0, stream>>>(dstp, degi);
    k_scan1<<<nsb, 256, 0, stream>>>(degi, rowptr, bsums);
    k_scan2<<<1, 128, 0, stream>>>(bsums, nsb);
    k_scan3<<<nsb, 256, 0, stream>>>(rowptr, bsums, degi, invd);
    k_fill<<<(NE + 255) / 256, 256, 0, stream>>>(srcp, dstp, rowptr, fill, col);

    // layer 1
    k_agg<<<NN, 64, 0, stream>>>((const float2*)x, col, rowptr, invd, (float2*)mean);
    k_gemm<<<(NN + 63) / 64, 256, 0, stream>>>(mean, x, Wl1, Wr1, b1, out, NN);
    // layer 2 (h lives in d_out; gemm blocks only read their own rows before writing)
    k_agg<<<NN, 64, 0, stream>>>((const float2*)out, col, rowptr, invd, (float2*)mean);
    k_gemm<<<(NN + 63) / 64, 256, 0, stream>>>(mean, out, Wl2, Wr2, b2, out, NN);
}

// Round 2
// 529.887 us; speedup vs baseline: 1.3026x; 1.3026x over previous
//
#include <hip/hip_runtime.h>

#define NN 100000
#define NE 1600000
#define CH 128

typedef __attribute__((ext_vector_type(8))) short bf16x8;
typedef __attribute__((ext_vector_type(4))) float f32x4;
typedef unsigned int uint;
typedef unsigned short ushort;

__device__ __forceinline__ ushort f2b(float f) {
    uint u = __builtin_bit_cast(uint, f);
    uint r = (u + 0x7fff + ((u >> 16) & 1)) >> 16;
    return (ushort)r;
}
__device__ __forceinline__ float blo(uint v) { return __builtin_bit_cast(float, v << 16); }
__device__ __forceinline__ float bhi(uint v) { return __builtin_bit_cast(float, v & 0xffff0000u); }

// ---------------- CSR build ----------------

__global__ __launch_bounds__(256) void k_count(const int* __restrict__ dst, int* __restrict__ degi) {
    int e = blockIdx.x * 256 + threadIdx.x;
    if (e < NE) atomicAdd(&degi[dst[e]], 1);
}

__global__ __launch_bounds__(256) void k_scan1(const int* __restrict__ degi, int* __restrict__ rowptr,
                                               int* __restrict__ bsums) {
    __shared__ int tsum[256];
    int tid = threadIdx.x;
    int base = blockIdx.x * 1024 + tid * 4;
    int v[4];
    #pragma unroll
    for (int j = 0; j < 4; ++j) v[j] = (base + j < NN) ? degi[base + j] : 0;
    int s = v[0] + v[1] + v[2] + v[3];
    tsum[tid] = s;
    __syncthreads();
    for (int off = 1; off < 256; off <<= 1) {
        int t = (tid >= off) ? tsum[tid - off] : 0;
        __syncthreads();
        tsum[tid] += t;
        __syncthreads();
    }
    int run = tsum[tid] - s;
    #pragma unroll
    for (int j = 0; j < 4; ++j) {
        if (base + j < NN) rowptr[base + j] = run;
        run += v[j];
    }
    if (tid == 255) bsums[blockIdx.x] = tsum[255];
}

__global__ __launch_bounds__(128) void k_scan2(int* __restrict__ bsums, int nsb) {
    __shared__ int sh[128];
    int tid = threadIdx.x;
    int v = (tid < nsb) ? bsums[tid] : 0;
    sh[tid] = v;
    __syncthreads();
    for (int off = 1; off < 128; off <<= 1) {
        int t = (tid >= off) ? sh[tid - off] : 0;
        __syncthreads();
        sh[tid] += t;
        __syncthreads();
    }
    if (tid < nsb) bsums[tid] = sh[tid] - v;
}

__global__ __launch_bounds__(256) void k_scan3(int* __restrict__ rowptr, const int* __restrict__ bsums,
                                               const int* __restrict__ degi, float* __restrict__ invd) {
    int b = blockIdx.x;
    int off = bsums[b];
    int tid = threadIdx.x;
    #pragma unroll
    for (int k = 0; k < 4; ++k) {
        int i = b * 1024 + k * 256 + tid;
        if (i < NN) {
            rowptr[i] += off;
            invd[i] = 1.0f / fmaxf((float)degi[i], 1.0f);
        }
    }
    if (b == 0 && tid == 0) rowptr[NN] = NE;
}

__global__ __launch_bounds__(256) void k_fill(const int* __restrict__ src, const int* __restrict__ dst,
                                              const int* __restrict__ rowptr, int* __restrict__ fill,
                                              int* __restrict__ col) {
    int e = blockIdx.x * 256 + threadIdx.x;
    if (e < NE) {
        int d = dst[e];
        int pos = rowptr[d] + atomicAdd(&fill[d], 1);
        col[pos] = src[e];
    }
}

// ---------------- casts ----------------

__global__ __launch_bounds__(256) void k_castx(const float4* __restrict__ in, ushort4* __restrict__ outb) {
    int i = blockIdx.x * 256 + threadIdx.x;  // over NN*32 float4s
    if (i < NN * 32) {
        float4 v = in[i];
        ushort4 r;
        r.x = f2b(v.x); r.y = f2b(v.y); r.z = f2b(v.z); r.w = f2b(v.w);
        outb[i] = r;
    }
}

// Bt[n][k] (n-major, K=256 contiguous): k<128 -> Wl[k][n], else Wr[k-128][n]
__global__ __launch_bounds__(256) void k_castw(const float* __restrict__ Wl, const float* __restrict__ Wr,
                                               ushort* __restrict__ Bt) {
    int i = blockIdx.x * 256 + threadIdx.x;  // 128*256
    int n = i >> 8, k = i & 255;
    float v = (k < 128) ? Wl[k * 128 + n] : Wr[(k - 128) * 128 + n];
    Bt[i] = f2b(v);
}

// ---------------- mean aggregation (bf16 in, bf16 out): one wave per node ----------------

__global__ __launch_bounds__(256) void k_agg(const uint* __restrict__ feat,  // [N][64] bf16-pairs
                                             const int* __restrict__ col, const int* __restrict__ rowptr,
                                             const float* __restrict__ invd, uint* __restrict__ outb) {
    int n = blockIdx.x * 4 + (threadIdx.x >> 6);
    int t = threadIdx.x & 63;
    if (n >= NN) return;
    int s = rowptr[n], e = rowptr[n + 1];
    float ax = 0.f, ay = 0.f;
    int i = s;
    for (; i + 4 <= e; i += 4) {  // 4 gathers in flight
        int c0 = col[i], c1 = col[i + 1], c2 = col[i + 2], c3 = col[i + 3];
        uint v0 = feat[(size_t)c0 * 64 + t];
        uint v1 = feat[(size_t)c1 * 64 + t];
        uint v2 = feat[(size_t)c2 * 64 + t];
        uint v3 = feat[(size_t)c3 * 64 + t];
        ax += blo(v0) + blo(v1) + blo(v2) + blo(v3);
        ay += bhi(v0) + bhi(v1) + bhi(v2) + bhi(v3);
    }
    for (; i < e; ++i) {
        uint v = feat[(size_t)col[i] * 64 + t];
        ax += blo(v);
        ay += bhi(v);
    }
    float id = invd[n];
    ax *= id;
    ay *= id;
    outb[(size_t)n * 64 + t] = (uint)f2b(ax) | ((uint)f2b(ay) << 16);
}

// ---------------- MFMA GEMM: out = relu([Am | Ax] @ Bt^T + bias) ----------------
// M x 128, K=256 (first 128 from Am, second from Ax). BM=128 per block (32 rows/wave).
// No LDS: A rows have zero cross-block reuse (full N per block); B is 64 KB, L2-hot.

template <bool WB16>
__global__ __launch_bounds__(256) void k_gemm(const ushort* __restrict__ Am, const ushort* Ax,
                                              const ushort* __restrict__ Bt, const float* __restrict__ bias,
                                              void* outp, int M) {
    int lane = threadIdx.x & 63;
    int wave = threadIdx.x >> 6;
    int bm = blockIdx.x * 128 + wave * 32;
    int l16 = lane & 15;
    int lk8 = (lane >> 4) * 8;

    f32x4 acc[2][8] = {};
    #pragma unroll
    for (int kt = 0; kt < 8; ++kt) {
        const ushort* A = (kt < 4) ? Am : Ax;
        int kA = (kt & 3) * 32 + lk8;
        bf16x8 af[2];
        #pragma unroll
        for (int mt = 0; mt < 2; ++mt) {
            int row = bm + mt * 16 + l16;
            row = row < M ? row : M - 1;
            af[mt] = *(const bf16x8*)(A + (size_t)row * 128 + kA);
        }
        int kB = kt * 32 + lk8;
        #pragma unroll
        for (int nt = 0; nt < 8; ++nt) {
            bf16x8 bfr = *(const bf16x8*)(Bt + (size_t)(nt * 16 + l16) * 256 + kB);
            acc[0][nt] = __builtin_amdgcn_mfma_f32_16x16x32_bf16(af[0], bfr, acc[0][nt], 0, 0, 0);
            acc[1][nt] = __builtin_amdgcn_mfma_f32_16x16x32_bf16(af[1], bfr, acc[1][nt], 0, 0, 0);
        }
    }
    // C/D layout: col = lane&15, row = (lane>>4)*4 + reg  [verified mapping]
    int mr0 = (lane >> 4) * 4;
    #pragma unroll
    for (int mt = 0; mt < 2; ++mt) {
        #pragma unroll
        for (int r = 0; r < 4; ++r) {
            int m = bm + mt * 16 + mr0 + r;
            if (m < M) {
                #pragma unroll
                for (int nt = 0; nt < 8; ++nt) {
                    int n = nt * 16 + l16;
                    float v = acc[mt][nt][r] + bias[n];
                    v = v > 0.f ? v : 0.f;
                    if (WB16)
                        ((ushort*)outp)[(size_t)m * 128 + n] = f2b(v);
                    else
                        ((float*)outp)[(size_t)m * 128 + n] = v;
                }
            }
        }
    }
}

// ---------------- launch ----------------

static inline size_t alignup(size_t x) { return (x + 255) & ~(size_t)255; }

extern "C" void kernel_launch(void* const* d_in, const int* in_sizes, int n_in,
                              void* d_out, int out_size, void* d_ws, size_t ws_size,
                              hipStream_t stream) {
    const float* x   = (const float*)d_in[0];
    const int* edge  = (const int*)d_in[1];
    const float* Wl1 = (const float*)d_in[2];
    const float* Wr1 = (const float*)d_in[3];
    const float* b1  = (const float*)d_in[4];
    const float* Wl2 = (const float*)d_in[5];
    const float* Wr2 = (const float*)d_in[6];
    const float* b2  = (const float*)d_in[7];
    float* out = (float*)d_out;

    const int* srcp = edge;
    const int* dstp = edge + NE;

    char* w = (char*)d_ws;
    int* degi = (int*)w;      w += alignup((size_t)NN * 4);
    int* fill = (int*)w;      w += alignup((size_t)NN * 4);
    int* rowptr = (int*)w;    w += alignup((size_t)(NN + 1) * 4);
    int* bsums = (int*)w;     w += alignup(128 * 4);
    float* invd = (float*)w;  w += alignup((size_t)NN * 4);
    int* col = (int*)w;       w += alignup((size_t)NE * 4);
    ushort* xb = (ushort*)w;  w += alignup((size_t)NN * CH * 2);  // also reused as h (bf16)
    ushort* mb = (ushort*)w;  w += alignup((size_t)NN * CH * 2);
    ushort* Bt1 = (ushort*)w; w += alignup((size_t)128 * 256 * 2);
    ushort* Bt2 = (ushort*)w; w += alignup((size_t)128 * 256 * 2);

    hipMemsetAsync(degi, 0, (size_t)NN * 4, stream);
    hipMemsetAsync(fill, 0, (size_t)NN * 4, stream);

    int nsb = (NN + 1023) / 1024;
    k_count<<<(NE + 255) / 256, 256, 0, stream>>>(dstp, degi);
    k_scan1<<<nsb, 256, 0, stream>>>(degi, rowptr, bsums);
    k_scan2<<<1, 128, 0, stream>>>(bsums, nsb);
    k_scan3<<<nsb, 256, 0, stream>>>(rowptr, bsums, degi, invd);
    k_fill<<<(NE + 255) / 256, 256, 0, stream>>>(srcp, dstp, rowptr, fill, col);

    k_castx<<<(NN * 32 + 255) / 256, 256, 0, stream>>>((const float4*)x, (ushort4*)xb);
    k_castw<<<128, 256, 0, stream>>>(Wl1, Wr1, Bt1);
    k_castw<<<128, 256, 0, stream>>>(Wl2, Wr2, Bt2);

    int gg = (NN + 127) / 128;
    // layer 1: agg(xb) -> mb; h = relu([mb|xb]@B1) written bf16 in place over xb
    k_agg<<<(NN + 3) / 4, 256, 0, stream>>>((const uint*)xb, col, rowptr, invd, (uint*)mb);
    k_gemm<true><<<gg, 256, 0, stream>>>(mb, xb, Bt1, b1, (void*)xb, NN);
    // layer 2: agg(h) -> mb; out = relu([mb|h]@B2) fp32
    k_agg<<<(NN + 3) / 4, 256, 0, stream>>>((const uint*)xb, col, rowptr, invd, (uint*)mb);
    k_gemm<false><<<gg, 256, 0, stream>>>(mb, xb, Bt2, b2, (void*)out, NN);
}

// Round 3
// 492.599 us; speedup vs baseline: 1.4012x; 1.0757x over previous
//
#include <hip/hip_runtime.h>

#define NN 100000
#define NE 1600000
#define CH 128

typedef __attribute__((ext_vector_type(8))) short bf16x8;
typedef __attribute__((ext_vector_type(4))) float f32x4;
typedef unsigned int uint;
typedef unsigned short ushort;

__device__ __forceinline__ ushort f2b(float f) {
    uint u = __builtin_bit_cast(uint, f);
    uint r = (u + 0x7fff + ((u >> 16) & 1)) >> 16;
    return (ushort)r;
}
__device__ __forceinline__ float blo(uint v) { return __builtin_bit_cast(float, v << 16); }
__device__ __forceinline__ float bhi(uint v) { return __builtin_bit_cast(float, v & 0xffff0000u); }

// ---------------- CSR build ----------------

// degree count + per-edge rank within its dst (rank write is coalesced)
__global__ __launch_bounds__(256) void k_count(const int* __restrict__ dst, int* __restrict__ degi,
                                               int* __restrict__ rank) {
    int e = blockIdx.x * 256 + threadIdx.x;
    if (e < NE) rank[e] = atomicAdd(&degi[dst[e]], 1);
}

__global__ __launch_bounds__(256) void k_scan1(const int* __restrict__ degi, int* __restrict__ rowptr,
                                               int* __restrict__ bsums) {
    __shared__ int tsum[256];
    int tid = threadIdx.x;
    int base = blockIdx.x * 1024 + tid * 4;
    int v[4];
    #pragma unroll
    for (int j = 0; j < 4; ++j) v[j] = (base + j < NN) ? degi[base + j] : 0;
    int s = v[0] + v[1] + v[2] + v[3];
    tsum[tid] = s;
    __syncthreads();
    for (int off = 1; off < 256; off <<= 1) {
        int t = (tid >= off) ? tsum[tid - off] : 0;
        __syncthreads();
        tsum[tid] += t;
        __syncthreads();
    }
    int run = tsum[tid] - s;
    #pragma unroll
    for (int j = 0; j < 4; ++j) {
        if (base + j < NN) rowptr[base + j] = run;
        run += v[j];
    }
    if (tid == 255) bsums[blockIdx.x] = tsum[255];
}

__global__ __launch_bounds__(128) void k_scan2(int* __restrict__ bsums, int nsb) {
    __shared__ int sh[128];
    int tid = threadIdx.x;
    int v = (tid < nsb) ? bsums[tid] : 0;
    sh[tid] = v;
    __syncthreads();
    for (int off = 1; off < 128; off <<= 1) {
        int t = (tid >= off) ? sh[tid - off] : 0;
        __syncthreads();
        sh[tid] += t;
        __syncthreads();
    }
    if (tid < nsb) bsums[tid] = sh[tid] - v;
}

__global__ __launch_bounds__(256) void k_scan3(int* __restrict__ rowptr, const int* __restrict__ bsums,
                                               const int* __restrict__ degi, float* __restrict__ invd) {
    int b = blockIdx.x;
    int off = bsums[b];
    int tid = threadIdx.x;
    #pragma unroll
    for (int k = 0; k < 4; ++k) {
        int i = b * 1024 + k * 256 + tid;
        if (i < NN) {
            rowptr[i] += off;
            invd[i] = 1.0f / fmaxf((float)degi[i], 1.0f);
        }
    }
    if (b == 0 && tid == 0) rowptr[NN] = NE;
}

// atomic-free fill: pos = rowptr[dst] + precomputed rank
__global__ __launch_bounds__(256) void k_fill(const int* __restrict__ src, const int* __restrict__ dst,
                                              const int* __restrict__ rowptr, const int* __restrict__ rank,
                                              int* __restrict__ col) {
    int e = blockIdx.x * 256 + threadIdx.x;
    if (e < NE) {
        col[rowptr[dst[e]] + rank[e]] = src[e];
    }
}

// ---------------- casts ----------------

// x [NN][128] fp32 -> plane-sliced bf16: xb[p][n][16], p = blockIdx.y
__global__ __launch_bounds__(256) void k_castx(const float* __restrict__ x, ushort* __restrict__ xb) {
    int n = blockIdx.x * 256 + threadIdx.x;
    int p = blockIdx.y;
    if (n >= NN) return;
    const float4* sp = (const float4*)(x + (size_t)n * 128 + p * 16);
    uint4 o[2];
    ushort* op = (ushort*)o;
    #pragma unroll
    for (int q = 0; q < 4; ++q) {
        float4 v = sp[q];
        op[q * 4 + 0] = f2b(v.x);
        op[q * 4 + 1] = f2b(v.y);
        op[q * 4 + 2] = f2b(v.z);
        op[q * 4 + 3] = f2b(v.w);
    }
    uint4* dp = (uint4*)(xb + ((size_t)p * NN + n) * 16);
    dp[0] = o[0];
    dp[1] = o[1];
}

// Bt[n][k] (n-major, K=256 contiguous): k<128 -> Wl[k][n], else Wr[k-128][n]
__global__ __launch_bounds__(256) void k_castw(const float* __restrict__ Wl, const float* __restrict__ Wr,
                                               ushort* __restrict__ Bt) {
    int i = blockIdx.x * 256 + threadIdx.x;  // 128*256
    int n = i >> 8, k = i & 255;
    float v = (k < 128) ? Wl[k * 128 + n] : Wr[(k - 128) * 128 + n];
    Bt[i] = f2b(v);
}

// ---------------- mean aggregation, plane-sliced ----------------
// grid (8, NN/32); plane = blockIdx.x so linear%8 pins plane<->XCD.
// 8 lanes per node (one 16-ch plane = 8 bf16-pairs), 32 nodes per block.

__global__ __launch_bounds__(256) void k_agg(const uint* __restrict__ feat, const int* __restrict__ col,
                                             const int* __restrict__ rowptr, const float* __restrict__ invd,
                                             uint* __restrict__ outb) {
    int plane = blockIdx.x;
    int n = blockIdx.y * 32 + (threadIdx.x >> 3);
    int cp = threadIdx.x & 7;
    if (n >= NN) return;
    int s = rowptr[n], e = rowptr[n + 1];
    const uint* fp = feat + (size_t)plane * NN * 8 + cp;
    float ax = 0.f, ay = 0.f;
    int i = s;
    for (; i + 4 <= e; i += 4) {
        int c0 = col[i], c1 = col[i + 1], c2 = col[i + 2], c3 = col[i + 3];
        uint v0 = fp[(size_t)c0 * 8];
        uint v1 = fp[(size_t)c1 * 8];
        uint v2 = fp[(size_t)c2 * 8];
        uint v3 = fp[(size_t)c3 * 8];
        ax += blo(v0) + blo(v1) + blo(v2) + blo(v3);
        ay += bhi(v0) + bhi(v1) + bhi(v2) + bhi(v3);
    }
    for (; i < e; ++i) {
        uint v = fp[(size_t)col[i] * 8];
        ax += blo(v);
        ay += bhi(v);
    }
    float id = invd[n];
    outb[((size_t)plane * NN + n) * 8 + cp] = (uint)f2b(ax * id) | ((uint)f2b(ay * id) << 16);
}

// ---------------- MFMA GEMM: out = relu([Am | Ax] @ Bt^T + bias) ----------------
// A operands plane-sliced [8][N][16] bf16. M x 128, K=256. BM=128/block, 32 rows/wave.

template <bool WB16>
__global__ __launch_bounds__(256) void k_gemm(const ushort* __restrict__ Am, const ushort* Ax,
                                              const ushort* __restrict__ Bt, const float* __restrict__ bias,
                                              void* outp, int M) {
    int lane = threadIdx.x & 63;
    int wave = threadIdx.x >> 6;
    int bm = blockIdx.x * 128 + wave * 32;
    int l16 = lane & 15;
    int lk8 = (lane >> 4) * 8;

    f32x4 acc[2][8] = {};
    #pragma unroll
    for (int kt = 0; kt < 8; ++kt) {
        const ushort* A = (kt < 4) ? Am : Ax;
        int kA = (kt & 3) * 32 + lk8;           // channel offset in [0,128), multiple of 8
        int p = kA >> 4, ko = kA & 15;          // plane, offset within plane row
        bf16x8 af[2];
        #pragma unroll
        for (int mt = 0; mt < 2; ++mt) {
            int row = bm + mt * 16 + l16;
            row = row < M ? row : M - 1;
            af[mt] = *(const bf16x8*)(A + ((size_t)p * NN + row) * 16 + ko);
        }
        int kB = kt * 32 + lk8;
        #pragma unroll
        for (int nt = 0; nt < 8; ++nt) {
            bf16x8 bfr = *(const bf16x8*)(Bt + (size_t)(nt * 16 + l16) * 256 + kB);
            acc[0][nt] = __builtin_amdgcn_mfma_f32_16x16x32_bf16(af[0], bfr, acc[0][nt], 0, 0, 0);
            acc[1][nt] = __builtin_amdgcn_mfma_f32_16x16x32_bf16(af[1], bfr, acc[1][nt], 0, 0, 0);
        }
    }
    // C/D layout: col = lane&15, row = (lane>>4)*4 + reg
    int mr0 = (lane >> 4) * 4;
    #pragma unroll
    for (int mt = 0; mt < 2; ++mt) {
        #pragma unroll
        for (int r = 0; r < 4; ++r) {
            int m = bm + mt * 16 + mr0 + r;
            if (m < M) {
                #pragma unroll
                for (int nt = 0; nt < 8; ++nt) {
                    float v = acc[mt][nt][r] + bias[nt * 16 + l16];
                    v = v > 0.f ? v : 0.f;
                    if (WB16) {
                        // h plane-sliced: plane = nt, ch = l16
                        ((ushort*)outp)[((size_t)nt * NN + m) * 16 + l16] = f2b(v);
                    } else {
                        ((float*)outp)[(size_t)m * 128 + nt * 16 + l16] = v;
                    }
                }
            }
        }
    }
}

// ---------------- launch ----------------

static inline size_t alignup(size_t x) { return (x + 255) & ~(size_t)255; }

extern "C" void kernel_launch(void* const* d_in, const int* in_sizes, int n_in,
                              void* d_out, int out_size, void* d_ws, size_t ws_size,
                              hipStream_t stream) {
    const float* x   = (const float*)d_in[0];
    const int* edge  = (const int*)d_in[1];
    const float* Wl1 = (const float*)d_in[2];
    const float* Wr1 = (const float*)d_in[3];
    const float* b1  = (const float*)d_in[4];
    const float* Wl2 = (const float*)d_in[5];
    const float* Wr2 = (const float*)d_in[6];
    const float* b2  = (const float*)d_in[7];
    float* out = (float*)d_out;

    const int* srcp = edge;
    const int* dstp = edge + NE;

    char* w = (char*)d_ws;
    int* degi = (int*)w;      w += alignup((size_t)NN * 4);
    int* rowptr = (int*)w;    w += alignup((size_t)(NN + 1) * 4);
    int* bsums = (int*)w;     w += alignup(128 * 4);
    float* invd = (float*)w;  w += alignup((size_t)NN * 4);
    int* col = (int*)w;       w += alignup((size_t)NE * 4);
    ushort* xb = (ushort*)w;  w += alignup((size_t)NN * CH * 2);  // plane-sliced; reused as h
    ushort* mb = (ushort*)w;  w += alignup((size_t)NN * CH * 2);  // plane-sliced mean
    ushort* Bt1 = (ushort*)w; w += alignup((size_t)128 * 256 * 2);
    ushort* Bt2 = (ushort*)w; w += alignup((size_t)128 * 256 * 2);
    int* rank = (int*)xb;  // aliases xb: rank dead before castx writes xb

    hipMemsetAsync(degi, 0, (size_t)NN * 4, stream);

    int nsb = (NN + 1023) / 1024;
    k_count<<<(NE + 255) / 256, 256, 0, stream>>>(dstp, degi, rank);
    k_scan1<<<nsb, 256, 0, stream>>>(degi, rowptr, bsums);
    k_scan2<<<1, 128, 0, stream>>>(bsums, nsb);
    k_scan3<<<nsb, 256, 0, stream>>>(rowptr, bsums, degi, invd);
    k_fill<<<(NE + 255) / 256, 256, 0, stream>>>(srcp, dstp, rowptr, rank, col);

    // casts after k_fill (rank aliases xb)
    k_castx<<<dim3((NN + 255) / 256, 8), 256, 0, stream>>>(x, xb);
    k_castw<<<128, 256, 0, stream>>>(Wl1, Wr1, Bt1);
    k_castw<<<128, 256, 0, stream>>>(Wl2, Wr2, Bt2);

    int gg = (NN + 127) / 128;
    dim3 ag(8, (NN + 31) / 32);
    // layer 1: agg(xb) -> mb; h = relu([mb|xb]@B1) bf16 plane-sliced, in place over xb
    k_agg<<<ag, 256, 0, stream>>>((const uint*)xb, col, rowptr, invd, (uint*)mb);
    k_gemm<true><<<gg, 256, 0, stream>>>(mb, xb, Bt1, b1, (void*)xb, NN);
    // layer 2: agg(h) -> mb; out = relu([mb|h]@B2) fp32 row-major
    k_agg<<<ag, 256, 0, stream>>>((const uint*)xb, col, rowptr, invd, (uint*)mb);
    k_gemm<false><<<gg, 256, 0, stream>>>(mb, xb, Bt2, b2, (void*)out, NN);
}

// Round 4
// 491.535 us; speedup vs baseline: 1.4043x; 1.0022x over previous
//
#include <hip/hip_runtime.h>

#define NN 100000
#define NE 1600000
#define CH 128

typedef __attribute__((ext_vector_type(8))) short bf16x8;
typedef __attribute__((ext_vector_type(4))) float f32x4;
typedef unsigned int uint;
typedef unsigned short ushort;

__device__ __forceinline__ ushort f2b(float f) {
    uint u = __builtin_bit_cast(uint, f);
    uint r = (u + 0x7fff + ((u >> 16) & 1)) >> 16;
    return (ushort)r;
}
__device__ __forceinline__ float blo(uint v) { return __builtin_bit_cast(float, v << 16); }
__device__ __forceinline__ float bhi(uint v) { return __builtin_bit_cast(float, v & 0xffff0000u); }

__device__ __forceinline__ void acc8(float* a, uint4 v) {
    a[0] += blo(v.x); a[1] += bhi(v.x);
    a[2] += blo(v.y); a[3] += bhi(v.y);
    a[4] += blo(v.z); a[5] += bhi(v.z);
    a[6] += blo(v.w); a[7] += bhi(v.w);
}

// ---------------- CSR build ----------------

// degree count + per-edge rank within its dst (rank write is coalesced)
__global__ __launch_bounds__(256) void k_count(const int* __restrict__ dst, int* __restrict__ degi,
                                               int* __restrict__ rank) {
    int e = blockIdx.x * 256 + threadIdx.x;
    if (e < NE) rank[e] = atomicAdd(&degi[dst[e]], 1);
}

__global__ __launch_bounds__(256) void k_scan1(const int* __restrict__ degi, int* __restrict__ rowptr,
                                               int* __restrict__ bsums) {
    __shared__ int tsum[256];
    int tid = threadIdx.x;
    int base = blockIdx.x * 1024 + tid * 4;
    int v[4];
    #pragma unroll
    for (int j = 0; j < 4; ++j) v[j] = (base + j < NN) ? degi[base + j] : 0;
    int s = v[0] + v[1] + v[2] + v[3];
    tsum[tid] = s;
    __syncthreads();
    for (int off = 1; off < 256; off <<= 1) {
        int t = (tid >= off) ? tsum[tid - off] : 0;
        __syncthreads();
        tsum[tid] += t;
        __syncthreads();
    }
    int run = tsum[tid] - s;
    #pragma unroll
    for (int j = 0; j < 4; ++j) {
        if (base + j < NN) rowptr[base + j] = run;
        run += v[j];
    }
    if (tid == 255) bsums[blockIdx.x] = tsum[255];
}

__global__ __launch_bounds__(128) void k_scan2(int* __restrict__ bsums, int nsb) {
    __shared__ int sh[128];
    int tid = threadIdx.x;
    int v = (tid < nsb) ? bsums[tid] : 0;
    sh[tid] = v;
    __syncthreads();
    for (int off = 1; off < 128; off <<= 1) {
        int t = (tid >= off) ? sh[tid - off] : 0;
        __syncthreads();
        sh[tid] += t;
        __syncthreads();
    }
    if (tid < nsb) bsums[tid] = sh[tid] - v;
}

__global__ __launch_bounds__(256) void k_scan3(int* __restrict__ rowptr, const int* __restrict__ bsums,
                                               const int* __restrict__ degi, float* __restrict__ invd) {
    int b = blockIdx.x;
    int off = bsums[b];
    int tid = threadIdx.x;
    #pragma unroll
    for (int k = 0; k < 4; ++k) {
        int i = b * 1024 + k * 256 + tid;
        if (i < NN) {
            rowptr[i] += off;
            invd[i] = 1.0f / fmaxf((float)degi[i], 1.0f);
        }
    }
    if (b == 0 && tid == 0) rowptr[NN] = NE;
}

// atomic-free fill: pos = rowptr[dst] + precomputed rank
__global__ __launch_bounds__(256) void k_fill(const int* __restrict__ src, const int* __restrict__ dst,
                                              const int* __restrict__ rowptr, const int* __restrict__ rank,
                                              int* __restrict__ col) {
    int e = blockIdx.x * 256 + threadIdx.x;
    if (e < NE) {
        col[rowptr[dst[e]] + rank[e]] = src[e];
    }
}

// ---------------- casts ----------------

// x [NN][128] fp32 -> plane-sliced bf16: xb[p][n][16], p = blockIdx.y
__global__ __launch_bounds__(256) void k_castx(const float* __restrict__ x, ushort* __restrict__ xb) {
    int n = blockIdx.x * 256 + threadIdx.x;
    int p = blockIdx.y;
    if (n >= NN) return;
    const float4* sp = (const float4*)(x + (size_t)n * 128 + p * 16);
    uint4 o[2];
    ushort* op = (ushort*)o;
    #pragma unroll
    for (int q = 0; q < 4; ++q) {
        float4 v = sp[q];
        op[q * 4 + 0] = f2b(v.x);
        op[q * 4 + 1] = f2b(v.y);
        op[q * 4 + 2] = f2b(v.z);
        op[q * 4 + 3] = f2b(v.w);
    }
    uint4* dp = (uint4*)(xb + ((size_t)p * NN + n) * 16);
    dp[0] = o[0];
    dp[1] = o[1];
}

// Bt[n][k] (n-major, K=256 contiguous): k<128 -> Wl[k][n], else Wr[k-128][n]
__global__ __launch_bounds__(256) void k_castw(const float* __restrict__ Wl, const float* __restrict__ Wr,
                                               ushort* __restrict__ Bt) {
    int i = blockIdx.x * 256 + threadIdx.x;  // 128*256
    int n = i >> 8, k = i & 255;
    float v = (k < 128) ? Wl[k * 128 + n] : Wr[(k - 128) * 128 + n];
    Bt[i] = f2b(v);
}

// ---------------- mean aggregation, plane-sliced, uint4 gathers ----------------
// grid (8, NN/128); plane = blockIdx.x so linear%8 pins plane<->XCD.
// 2 lanes per node (one 16-ch plane = 2 x uint4), 128 nodes per block.

__global__ __launch_bounds__(256) void k_agg(const uint4* __restrict__ feat, const int* __restrict__ col,
                                             const int* __restrict__ rowptr, const float* __restrict__ invd,
                                             uint4* __restrict__ outb) {
    int plane = blockIdx.x;
    int n = blockIdx.y * 128 + (threadIdx.x >> 1);
    int h = threadIdx.x & 1;
    if (n >= NN) return;
    int s = rowptr[n], e = rowptr[n + 1];
    const uint4* fp = feat + (size_t)plane * (NN * 2) + h;
    float a[8] = {};
    int i = s;
    for (; i + 4 <= e; i += 4) {  // 4 x 16B gathers in flight per lane
        int c0 = col[i], c1 = col[i + 1], c2 = col[i + 2], c3 = col[i + 3];
        uint4 v0 = fp[(size_t)c0 * 2];
        uint4 v1 = fp[(size_t)c1 * 2];
        uint4 v2 = fp[(size_t)c2 * 2];
        uint4 v3 = fp[(size_t)c3 * 2];
        acc8(a, v0);
        acc8(a, v1);
        acc8(a, v2);
        acc8(a, v3);
    }
    for (; i < e; ++i) acc8(a, fp[(size_t)col[i] * 2]);
    float id = invd[n];
    uint4 r;
    r.x = (uint)f2b(a[0] * id) | ((uint)f2b(a[1] * id) << 16);
    r.y = (uint)f2b(a[2] * id) | ((uint)f2b(a[3] * id) << 16);
    r.z = (uint)f2b(a[4] * id) | ((uint)f2b(a[5] * id) << 16);
    r.w = (uint)f2b(a[6] * id) | ((uint)f2b(a[7] * id) << 16);
    outb[((size_t)plane * NN + n) * 2 + h] = r;
}

// ---------------- MFMA GEMM: out = relu([Am | Ax] @ Bt^T + bias) ----------------
// A operands plane-sliced [8][N][16] bf16. M x 128, K=256. BM=128/block, 32 rows/wave.

template <bool WB16>
__global__ __launch_bounds__(256) void k_gemm(const ushort* __restrict__ Am, const ushort* Ax,
                                              const ushort* __restrict__ Bt, const float* __restrict__ bias,
                                              void* outp, int M) {
    int lane = threadIdx.x & 63;
    int wave = threadIdx.x >> 6;
    int bm = blockIdx.x * 128 + wave * 32;
    int l16 = lane & 15;
    int lk8 = (lane >> 4) * 8;

    f32x4 acc[2][8] = {};
    #pragma unroll
    for (int kt = 0; kt < 8; ++kt) {
        const ushort* A = (kt < 4) ? Am : Ax;
        int kA = (kt & 3) * 32 + lk8;           // channel offset in [0,128), multiple of 8
        int p = kA >> 4, ko = kA & 15;          // plane, offset within plane row
        bf16x8 af[2];
        #pragma unroll
        for (int mt = 0; mt < 2; ++mt) {
            int row = bm + mt * 16 + l16;
            row = row < M ? row : M - 1;
            af[mt] = *(const bf16x8*)(A + ((size_t)p * NN + row) * 16 + ko);
        }
        int kB = kt * 32 + lk8;
        #pragma unroll
        for (int nt = 0; nt < 8; ++nt) {
            bf16x8 bfr = *(const bf16x8*)(Bt + (size_t)(nt * 16 + l16) * 256 + kB);
            acc[0][nt] = __builtin_amdgcn_mfma_f32_16x16x32_bf16(af[0], bfr, acc[0][nt], 0, 0, 0);
            acc[1][nt] = __builtin_amdgcn_mfma_f32_16x16x32_bf16(af[1], bfr, acc[1][nt], 0, 0, 0);
        }
    }
    // C/D layout: col = lane&15, row = (lane>>4)*4 + reg
    int mr0 = (lane >> 4) * 4;
    #pragma unroll
    for (int mt = 0; mt < 2; ++mt) {
        #pragma unroll
        for (int r = 0; r < 4; ++r) {
            int m = bm + mt * 16 + mr0 + r;
            if (m < M) {
                #pragma unroll
                for (int nt = 0; nt < 8; ++nt) {
                    float v = acc[mt][nt][r] + bias[nt * 16 + l16];
                    v = v > 0.f ? v : 0.f;
                    if (WB16) {
                        // h plane-sliced: plane = nt, ch = l16
                        ((ushort*)outp)[((size_t)nt * NN + m) * 16 + l16] = f2b(v);
                    } else {
                        ((float*)outp)[(size_t)m * 128 + nt * 16 + l16] = v;
                    }
                }
            }
        }
    }
}

// ---------------- launch ----------------

static inline size_t alignup(size_t x) { return (x + 255) & ~(size_t)255; }

extern "C" void kernel_launch(void* const* d_in, const int* in_sizes, int n_in,
                              void* d_out, int out_size, void* d_ws, size_t ws_size,
                              hipStream_t stream) {
    const float* x   = (const float*)d_in[0];
    const int* edge  = (const int*)d_in[1];
    const float* Wl1 = (const float*)d_in[2];
    const float* Wr1 = (const float*)d_in[3];
    const float* b1  = (const float*)d_in[4];
    const float* Wl2 = (const float*)d_in[5];
    const float* Wr2 = (const float*)d_in[6];
    const float* b2  = (const float*)d_in[7];
    float* out = (float*)d_out;

    const int* srcp = edge;
    const int* dstp = edge + NE;

    char* w = (char*)d_ws;
    int* degi = (int*)w;      w += alignup((size_t)NN * 4);
    int* rowptr = (int*)w;    w += alignup((size_t)(NN + 1) * 4);
    int* bsums = (int*)w;     w += alignup(128 * 4);
    float* invd = (float*)w;  w += alignup((size_t)NN * 4);
    int* col = (int*)w;       w += alignup((size_t)NE * 4);
    ushort* xb = (ushort*)w;  w += alignup((size_t)NN * CH * 2);  // plane-sliced; reused as h
    ushort* mb = (ushort*)w;  w += alignup((size_t)NN * CH * 2);  // plane-sliced mean
    ushort* Bt1 = (ushort*)w; w += alignup((size_t)128 * 256 * 2);
    ushort* Bt2 = (ushort*)w; w += alignup((size_t)128 * 256 * 2);
    int* rank = (int*)xb;  // aliases xb: rank dead before castx writes xb

    hipMemsetAsync(degi, 0, (size_t)NN * 4, stream);

    int nsb = (NN + 1023) / 1024;
    k_count<<<(NE + 255) / 256, 256, 0, stream>>>(dstp, degi, rank);
    k_scan1<<<nsb, 256, 0, stream>>>(degi, rowptr, bsums);
    k_scan2<<<1, 128, 0, stream>>>(bsums, nsb);
    k_scan3<<<nsb, 256, 0, stream>>>(rowptr, bsums, degi, invd);
    k_fill<<<(NE + 255) / 256, 256, 0, stream>>>(srcp, dstp, rowptr, rank, col);

    // casts after k_fill (rank aliases xb)
    k_castx<<<dim3((NN + 255) / 256, 8), 256, 0, stream>>>(x, xb);
    k_castw<<<128, 256, 0, stream>>>(Wl1, Wr1, Bt1);
    k_castw<<<128, 256, 0, stream>>>(Wl2, Wr2, Bt2);

    int gg = (NN + 127) / 128;
    dim3 ag(8, (NN + 127) / 128);
    // layer 1: agg(xb) -> mb; h = relu([mb|xb]@B1) bf16 plane-sliced, in place over xb
    k_agg<<<ag, 256, 0, stream>>>((const uint4*)xb, col, rowptr, invd, (uint4*)mb);
    k_gemm<true><<<gg, 256, 0, stream>>>(mb, xb, Bt1, b1, (void*)xb, NN);
    // layer 2: agg(h) -> mb; out = relu([mb|h]@B2) fp32 row-major
    k_agg<<<ag, 256, 0, stream>>>((const uint4*)xb, col, rowptr, invd, (uint4*)mb);
    k_gemm<false><<<gg, 256, 0, stream>>>(mb, xb, Bt2, b2, (void*)out, NN);
}